// Round 6
// baseline (485.329 us; speedup 1.0000x reference)
//
#include <hip/hip_runtime.h>
#include <hip/hip_fp16.h>
#include <hip/hip_cooperative_groups.h>
#include <math.h>

namespace cg = cooperative_groups;

#define N_ATOMS 512
#define F_DIM   128
#define K_RBF   301
#define NLAYER  3
#define GAMMA_C 10.0f
#define LOG2_C  0.6931471805599453f

// Filter lookup table: w_l(d) sampled at step TAB_H; max d = 10*sqrt(3) = 17.32
#define TAB_H     0.01f
#define TAB_INVH  100.0f
#define TAB_ROWS  1768          // 221 * 8, covers up to 17.67
#define RPB       8             // table rows emitted per task (computes RPB+1)
#define NGROUPS   (TAB_ROWS / RPB)          // 221
#define NTASKS    (NGROUPS * NLAYER)        // 663 (row-group, layer) tasks
#define NBBLK2    ((NTASKS + 1) / 2)        // 332 build blocks, 2 tasks each
#define ROW_BYTES 512           // 64 f-pairs * 8 B (uint2 per pair)

__device__ __forceinline__ float ssp(float x) {
    float ax = fabsf(x);
    return fmaxf(x, 0.0f) + log1pf(expf(-ax)) - LOG2_C;
}
__device__ __forceinline__ __half2 u2h2(unsigned u) {
    union { unsigned u; __half2 h; } c; c.u = u; return c.h;
}
__device__ __forceinline__ unsigned h22u(__half2 h) {
    union { unsigned u; __half2 h; } c; c.h = h; return c.u;
}

// ===========================================================================
// LDS overlays for the fused cooperative kernel. Build and conv phases are
// time-separated by barriers.  Union size = 14,736 B -> even a pessimistic
// 64 KB-LDS occupancy model gives >=2 blocks/CU (512 blocks co-resident).
struct BuildS {                       // 14,736 B
    float e_s [2][RPB + 1][34];       //  2,448
    float w1_s[2][F_DIM][12];         // 12,288  [f][rr], 9 used, 48B rows
};
struct ConvS {                        //  7,680 B
    uint2  ds[N_ATOMS];               //  4,096
    float2 red[4][64];                //  2,048
    float  cs[F_DIM];                 //    512
    float  t1s[F_DIM];                //    512
    float  hs[F_DIM];                 //    512
};

__global__ void __launch_bounds__(256)
fused_kernel(const int* __restrict__ x, const float* __restrict__ r,
             const float* __restrict__ emb,
             const float* __restrict__ aw_W, const float* __restrict__ aw_b,
             const float* __restrict__ cf_W1, const float* __restrict__ cf_b1,
             const float* __restrict__ cf_W2, const float* __restrict__ cf_b2,
             const float* __restrict__ n_W1, const float* __restrict__ n_b1,
             const float* __restrict__ n_W2, const float* __restrict__ n_b2,
             const float* __restrict__ oW1, const float* __restrict__ ob1,
             const float* __restrict__ oW2, const float* __restrict__ ob2,
             uint2* __restrict__ dpk, float* __restrict__ h,
             unsigned* __restrict__ opkA, unsigned* __restrict__ opkB,
             uint2* __restrict__ ptab, float* __restrict__ out) {
    cg::grid_group grid = cg::this_grid();
    __shared__ __align__(16) char smem[sizeof(BuildS)];
    BuildS& B = *reinterpret_cast<BuildS*>(smem);
    ConvS&  C = *reinterpret_cast<ConvS*>(smem);

    int i = blockIdx.x;
    int t = threadIdx.x;

    // ================= phase 1: prep (all blocks; block i = atom i) ========
    {
        float rx = r[i * 3 + 0], ry = r[i * 3 + 1], rz = r[i * 3 + 2];
        if (t < F_DIM) {
            float hv = emb[x[i] * F_DIM + t];
            h[i * F_DIM + t] = hv;
            C.hs[t] = hv;
        }
        for (int j = t; j < N_ATOMS; j += 256) {
            float dx = rx - r[j * 3 + 0];
            float dy = ry - r[j * 3 + 1];
            float dz = rz - r[j * 3 + 2];
            float d  = sqrtf(dx * dx + dy * dy + dz * dz);
            float xb = d * TAB_INVH;
            int   b  = ::min((int)xb, TAB_ROWS - 2);
            float fr = xb - (float)b;
            __half fh = __float2half(fr);
            dpk[i * N_ATOMS + j] = make_uint2((unsigned)b * ROW_BYTES,
                                              h22u(__halves2half2(fh, fh)));
        }
        __syncthreads();
        if (t < F_DIM) {
            float acc = aw_b[t];
            for (int g = 0; g < F_DIM; ++g) acc = fmaf(C.hs[g], aw_W[g * F_DIM + t], acc);
            C.t1s[t] = acc;
        }
        __syncthreads();
        if (t < F_DIM / 2)
            opkA[i * 64 + t] = h22u(__halves2half2(__float2half(C.t1s[2 * t]),
                                                   __float2half(C.t1s[2 * t + 1])));
    }
    __syncthreads();   // ConvS use done before BuildS overwrites the alias

    // ================= phase 2: table build (blocks 0..331, 2 tasks) =======
    if (i < NBBLK2) {
        int u = t >> 7;                  // task unit 0/1 (128 threads each)
        int f = t & 127;
        int task = i * 2 + u;
        bool valid = task < NTASKS;
        task = valid ? task : NTASKS - 1;
        int l    = task / NGROUPS;
        int row0 = (task % NGROUPS) * RPB;

        float dlo = row0 * TAB_H;
        float dhi = (row0 + RPB) * TAB_H;
        // Gaussian window: exp(-10*1.45^2) ~ 7.6e-10 truncation
        int k0 = ::max(0, (int)ceilf((dlo - 1.45f) * 10.0f));
        int k1 = ::min(K_RBF - 1, (int)floorf((dhi + 1.45f) * 10.0f));
        int kw = k1 - k0 + 1;   // <= ~31

        for (int idx = f; idx < (RPB + 1) * kw; idx += F_DIM) {
            int rr = idx / kw, kk = idx % kw;
            float dv = (row0 + rr) * TAB_H;
            float tt = dv - 0.1f * (float)(k0 + kk);
            B.e_s[u][rr][kk] = expf(-GAMMA_C * tt * tt);
        }
        __syncthreads();

        const float* W1 = cf_W1 + l * K_RBF * F_DIM;
        float b1v = cf_b1[l * F_DIM + f];
        float acc[RPB + 1];
#pragma unroll
        for (int rr = 0; rr <= RPB; ++rr) acc[rr] = b1v;
        for (int kk = 0; kk < kw; ++kk) {
            float w1v = W1[(k0 + kk) * F_DIM + f];
#pragma unroll
            for (int rr = 0; rr <= RPB; ++rr) acc[rr] = fmaf(B.e_s[u][rr][kk], w1v, acc[rr]);
        }
#pragma unroll
        for (int rr = 0; rr <= RPB; ++rr) B.w1_s[u][f][rr] = ssp(acc[rr]);
        __syncthreads();

        const float* W2 = cf_W2 + l * F_DIM * F_DIM;
        float b2v = cf_b2[l * F_DIM + f];
        float acc2[RPB + 1];
#pragma unroll
        for (int rr = 0; rr <= RPB; ++rr) acc2[rr] = b2v;
        for (int g = 0; g < F_DIM; ++g) {
            float w2v = W2[g * F_DIM + f];
            float4 wa = *(const float4*)&B.w1_s[u][g][0];   // broadcast reads
            float4 wb = *(const float4*)&B.w1_s[u][g][4];
            float  wc = B.w1_s[u][g][8];
            acc2[0] = fmaf(wa.x, w2v, acc2[0]);
            acc2[1] = fmaf(wa.y, w2v, acc2[1]);
            acc2[2] = fmaf(wa.z, w2v, acc2[2]);
            acc2[3] = fmaf(wa.w, w2v, acc2[3]);
            acc2[4] = fmaf(wb.x, w2v, acc2[4]);
            acc2[5] = fmaf(wb.y, w2v, acc2[5]);
            acc2[6] = fmaf(wb.z, w2v, acc2[6]);
            acc2[7] = fmaf(wb.w, w2v, acc2[7]);
            acc2[8] = fmaf(wc,   w2v, acc2[8]);
        }
        float o9[RPB + 1];
#pragma unroll
        for (int rr = 0; rr <= RPB; ++rr) o9[rr] = ssp(acc2[rr]);

        // pack via same-wave shfl with lane f^1 (2p/2p+1 adjacent); even lanes
        // write pair p = f>>1.  No LDS staging needed.
        if (valid) {
            int p = f >> 1;
            bool odd = (f & 1);
#pragma unroll
            for (int rr = 0; rr < RPB; ++rr) {
                float t0 = o9[rr];
                float dt = o9[rr + 1] - o9[rr];
                float ot0 = __shfl_xor(t0, 1, 64);
                float odt = __shfl_xor(dt, 1, 64);
                if (!odd) {
                    uint2 v = make_uint2(
                        h22u(__halves2half2(__float2half(t0), __float2half(ot0))),
                        h22u(__halves2half2(__float2half(dt), __float2half(odt))));
                    ptab[((size_t)l * TAB_ROWS + row0 + rr) * 64 + p] = v;
                }
            }
        }
    }

    __threadfence();   // publish ptab/opkA/dpk device-wide (cross-XCD)
    grid.sync();

    // ================= phase 3: layers (all blocks; block i = atom i) ======
    int p  = t & 63;
    int jc = t >> 6;            // 0..3

    for (int l = 0; l < NLAYER; ++l) {
        // reload per layer (build phase clobbered the LDS alias in blocks<332)
        for (int j = t; j < N_ATOMS; j += 256) C.ds[j] = dpk[i * N_ATOMS + j];
        if (t < F_DIM) C.hs[t] = h[i * F_DIM + t];
        __syncthreads();

        const unsigned* oin  = (l & 1) ? opkB : opkA;
        unsigned*       oout = (l & 1) ? opkA : opkB;

        // ---- conv ----
        const char* T = (const char*)(ptab + (size_t)l * TAB_ROWS * 64) + p * 8;
        float2 acc = make_float2(0.0f, 0.0f);
        int j = jc * 128;
#pragma unroll 4
        for (int jj = 0; jj < 128; ++jj, ++j) {
            uint2 e = C.ds[j];                       // broadcast: wave-uniform j
            uint2 tv = *(const uint2*)(T + e.x);     // {half2 t0, half2 dt}
            __half2 w2 = __hfma2(u2h2(e.y), u2h2(tv.y), u2h2(tv.x));
            __half2 oh = u2h2(oin[j * 64 + p]);
            acc.x = fmaf(__half2float(__low2half(w2)),  __half2float(__low2half(oh)),  acc.x);
            acc.y = fmaf(__half2float(__high2half(w2)), __half2float(__high2half(oh)), acc.y);
        }
        C.red[jc][p] = acc;
        __syncthreads();
        if (jc == 0) {
            float2 s = C.red[0][p];
#pragma unroll
            for (int q = 1; q < 4; ++q) { s.x += C.red[q][p].x; s.y += C.red[q][p].y; }
            *(float2*)&C.cs[2 * p] = s;
        }
        __syncthreads();

        // ---- node MLP ----
        if (t < F_DIM) {
            const float* W1 = n_W1 + l * F_DIM * F_DIM;
            float a = n_b1[l * F_DIM + t];
            for (int g = 0; g < F_DIM; ++g) a = fmaf(C.cs[g], W1[g * F_DIM + t], a);
            C.t1s[t] = ssp(a);
        }
        __syncthreads();
        if (t < F_DIM) {
            const float* W2 = n_W2 + l * F_DIM * F_DIM;
            float a2 = n_b2[l * F_DIM + t];
            for (int g = 0; g < F_DIM; ++g) a2 = fmaf(C.t1s[g], W2[g * F_DIM + t], a2);
            float hv = C.hs[t] + a2;            // own element only: safe
            h[i * F_DIM + t] = hv;
            C.hs[t] = hv;
        }
        __syncthreads();

        if (l < NLAYER - 1) {
            // next layer's atom-wise linear, packed to half2
            if (t < F_DIM) {
                const float* W = aw_W + (l + 1) * F_DIM * F_DIM;
                float a = aw_b[(l + 1) * F_DIM + t];
                for (int g = 0; g < F_DIM; ++g) a = fmaf(C.hs[g], W[g * F_DIM + t], a);
                C.cs[t] = a;                    // cs free after node-W1
            }
            __syncthreads();
            if (t < F_DIM / 2)
                oout[i * 64 + t] = h22u(__halves2half2(__float2half(C.cs[2 * t]),
                                                       __float2half(C.cs[2 * t + 1])));
            __threadfence();                    // publish oout before next layer
            grid.sync();
        } else {
            // output head
            float val = 0.0f;
            if (t < 32) {
                float ah = ob1[t];
                for (int g = 0; g < F_DIM; ++g) ah = fmaf(C.hs[g], oW1[g * 32 + t], ah);
                val = ssp(ah) * oW2[t];
            }
#pragma unroll
            for (int off = 16; off > 0; off >>= 1) val += __shfl_xor(val, off, 64);
            if (t == 0) out[i] = val + ob2[0];
        }
    }
}

// ===========================================================================
// FALLBACK path (round-4 structure, proven 169 us) — used only if the
// cooperative launch is rejected (deterministic, so same work every call).
__global__ void __launch_bounds__(256)
prep_build(const int* __restrict__ x, const float* __restrict__ r,
           const float* __restrict__ emb,
           const float* __restrict__ aw_W, const float* __restrict__ aw_b,
           const float* __restrict__ cf_W1, const float* __restrict__ cf_b1,
           const float* __restrict__ cf_W2, const float* __restrict__ cf_b2,
           uint2* __restrict__ dpk, float* __restrict__ h,
           unsigned* __restrict__ opk, uint2* __restrict__ ptab) {
    __shared__ float hs[F_DIM];
    __shared__ float os[F_DIM];
    __shared__ float e_s[2][RPB + 1][34];
    __shared__ float w1_s[2][F_DIM][12];

    if (blockIdx.x < N_ATOMS) {
        int i = blockIdx.x;
        int t = threadIdx.x;
        float rx = r[i * 3 + 0], ry = r[i * 3 + 1], rz = r[i * 3 + 2];
        if (t < F_DIM) {
            float hv = emb[x[i] * F_DIM + t];
            h[i * F_DIM + t] = hv;
            hs[t] = hv;
        }
        for (int j = t; j < N_ATOMS; j += 256) {
            float dx = rx - r[j * 3 + 0];
            float dy = ry - r[j * 3 + 1];
            float dz = rz - r[j * 3 + 2];
            float d  = sqrtf(dx * dx + dy * dy + dz * dz);
            float xb = d * TAB_INVH;
            int   b  = ::min((int)xb, TAB_ROWS - 2);
            float fr = xb - (float)b;
            __half fh = __float2half(fr);
            dpk[i * N_ATOMS + j] = make_uint2((unsigned)b * ROW_BYTES,
                                              h22u(__halves2half2(fh, fh)));
        }
        __syncthreads();
        if (t < F_DIM) {
            float acc = aw_b[t];
            for (int g = 0; g < F_DIM; ++g) acc = fmaf(hs[g], aw_W[g * F_DIM + t], acc);
            os[t] = acc;
        }
        __syncthreads();
        if (t < F_DIM / 2)
            opk[i * 64 + t] = h22u(__halves2half2(__float2half(os[2 * t]),
                                                  __float2half(os[2 * t + 1])));
        return;
    }

    int u = threadIdx.x >> 7;
    int f = threadIdx.x & 127;
    int task = (blockIdx.x - N_ATOMS) * 2 + u;
    bool valid = task < NTASKS;
    task = valid ? task : NTASKS - 1;
    int l    = task / NGROUPS;
    int row0 = (task % NGROUPS) * RPB;

    float dlo = row0 * TAB_H;
    float dhi = (row0 + RPB) * TAB_H;
    int k0 = ::max(0, (int)ceilf((dlo - 1.45f) * 10.0f));
    int k1 = ::min(K_RBF - 1, (int)floorf((dhi + 1.45f) * 10.0f));
    int kw = k1 - k0 + 1;

    for (int idx = f; idx < (RPB + 1) * kw; idx += F_DIM) {
        int rr = idx / kw, kk = idx % kw;
        float dv = (row0 + rr) * TAB_H;
        float tt = dv - 0.1f * (float)(k0 + kk);
        e_s[u][rr][kk] = expf(-GAMMA_C * tt * tt);
    }
    __syncthreads();

    const float* W1 = cf_W1 + l * K_RBF * F_DIM;
    float b1v = cf_b1[l * F_DIM + f];
    float acc[RPB + 1];
#pragma unroll
    for (int rr = 0; rr <= RPB; ++rr) acc[rr] = b1v;
    for (int kk = 0; kk < kw; ++kk) {
        float w1v = W1[(k0 + kk) * F_DIM + f];
#pragma unroll
        for (int rr = 0; rr <= RPB; ++rr) acc[rr] = fmaf(e_s[u][rr][kk], w1v, acc[rr]);
    }
#pragma unroll
    for (int rr = 0; rr <= RPB; ++rr) w1_s[u][f][rr] = ssp(acc[rr]);
    __syncthreads();

    const float* W2 = cf_W2 + l * F_DIM * F_DIM;
    float b2v = cf_b2[l * F_DIM + f];
    float acc2[RPB + 1];
#pragma unroll
    for (int rr = 0; rr <= RPB; ++rr) acc2[rr] = b2v;
    for (int g = 0; g < F_DIM; ++g) {
        float w2v = W2[g * F_DIM + f];
        float4 wa = *(const float4*)&w1_s[u][g][0];
        float4 wb = *(const float4*)&w1_s[u][g][4];
        float  wc = w1_s[u][g][8];
        acc2[0] = fmaf(wa.x, w2v, acc2[0]);
        acc2[1] = fmaf(wa.y, w2v, acc2[1]);
        acc2[2] = fmaf(wa.z, w2v, acc2[2]);
        acc2[3] = fmaf(wa.w, w2v, acc2[3]);
        acc2[4] = fmaf(wb.x, w2v, acc2[4]);
        acc2[5] = fmaf(wb.y, w2v, acc2[5]);
        acc2[6] = fmaf(wb.z, w2v, acc2[6]);
        acc2[7] = fmaf(wb.w, w2v, acc2[7]);
        acc2[8] = fmaf(wc,   w2v, acc2[8]);
    }
    float o9[RPB + 1];
#pragma unroll
    for (int rr = 0; rr <= RPB; ++rr) o9[rr] = ssp(acc2[rr]);

    if (valid) {
        int p = f >> 1;
        bool odd = (f & 1);
#pragma unroll
        for (int rr = 0; rr < RPB; ++rr) {
            float t0 = o9[rr];
            float dt = o9[rr + 1] - o9[rr];
            float ot0 = __shfl_xor(t0, 1, 64);
            float odt = __shfl_xor(dt, 1, 64);
            if (!odd) {
                uint2 v = make_uint2(
                    h22u(__halves2half2(__float2half(t0), __float2half(ot0))),
                    h22u(__halves2half2(__float2half(dt), __float2half(odt))));
                ptab[((size_t)l * TAB_ROWS + row0 + rr) * 64 + p] = v;
            }
        }
    }
}

__global__ void __launch_bounds__(512)
convnode_kernel(const uint2* __restrict__ dpk, const unsigned* __restrict__ opk_in,
                const uint2* __restrict__ ptab,
                const float* __restrict__ n_W1, const float* __restrict__ n_b1,
                const float* __restrict__ n_W2, const float* __restrict__ n_b2,
                float* __restrict__ h,
                const float* __restrict__ aw_W, const float* __restrict__ aw_b,
                unsigned* __restrict__ opk_out,
                const float* __restrict__ oW1, const float* __restrict__ ob1,
                const float* __restrict__ oW2, const float* __restrict__ ob2,
                float* __restrict__ out, int l) {
    int i  = blockIdx.x;
    int t  = threadIdx.x;
    int p  = t & 63;
    int jc = t >> 6;

    __shared__ uint2  ds[N_ATOMS];
    __shared__ float2 red[8][64];
    __shared__ float  cs[F_DIM];
    __shared__ float  t1s[F_DIM];
    __shared__ float  hs[F_DIM];

    ds[t] = dpk[i * N_ATOMS + t];
    if (t < F_DIM) hs[t] = h[i * F_DIM + t];
    __syncthreads();

    const char* T = (const char*)(ptab + (size_t)l * TAB_ROWS * 64) + p * 8;
    float2 acc = make_float2(0.0f, 0.0f);
    int j = jc * 64;
#pragma unroll 4
    for (int jj = 0; jj < 64; ++jj, ++j) {
        uint2 e = ds[j];
        uint2 tv = *(const uint2*)(T + e.x);
        __half2 w2 = __hfma2(u2h2(e.y), u2h2(tv.y), u2h2(tv.x));
        __half2 oh = u2h2(opk_in[j * 64 + p]);
        acc.x = fmaf(__half2float(__low2half(w2)),  __half2float(__low2half(oh)),  acc.x);
        acc.y = fmaf(__half2float(__high2half(w2)), __half2float(__high2half(oh)), acc.y);
    }
    red[jc][p] = acc;
    __syncthreads();
    if (jc == 0) {
        float2 s = red[0][p];
#pragma unroll
        for (int q = 1; q < 8; ++q) { s.x += red[q][p].x; s.y += red[q][p].y; }
        *(float2*)&cs[2 * p] = s;
    }
    __syncthreads();

    if (t < F_DIM) {
        const float* W1 = n_W1 + l * F_DIM * F_DIM;
        float a = n_b1[l * F_DIM + t];
        for (int g = 0; g < F_DIM; ++g) a = fmaf(cs[g], W1[g * F_DIM + t], a);
        t1s[t] = ssp(a);
    }
    __syncthreads();
    if (t < F_DIM) {
        const float* W2 = n_W2 + l * F_DIM * F_DIM;
        float a2 = n_b2[l * F_DIM + t];
        for (int g = 0; g < F_DIM; ++g) a2 = fmaf(t1s[g], W2[g * F_DIM + t], a2);
        float hv = hs[t] + a2;
        h[i * F_DIM + t] = hv;
        hs[t] = hv;
    }
    __syncthreads();

    if (l < NLAYER - 1) {
        if (t < F_DIM) {
            const float* W = aw_W + (l + 1) * F_DIM * F_DIM;
            float a = aw_b[(l + 1) * F_DIM + t];
            for (int g = 0; g < F_DIM; ++g) a = fmaf(hs[g], W[g * F_DIM + t], a);
            t1s[t] = a;
        }
        __syncthreads();
        if (t < F_DIM / 2)
            opk_out[i * 64 + t] = h22u(__halves2half2(__float2half(t1s[2 * t]),
                                                      __float2half(t1s[2 * t + 1])));
    } else {
        float val = 0.0f;
        if (t < 32) {
            float ah = ob1[t];
            for (int g = 0; g < F_DIM; ++g) ah = fmaf(hs[g], oW1[g * 32 + t], ah);
            val = ssp(ah) * oW2[t];
        }
#pragma unroll
        for (int off = 16; off > 0; off >>= 1) val += __shfl_xor(val, off, 64);
        if (t == 0) out[i] = val + ob2[0];
    }
}

// ---------------------------------------------------------------------------
extern "C" void kernel_launch(void* const* d_in, const int* in_sizes, int n_in,
                              void* d_out, int out_size, void* d_ws, size_t ws_size,
                              hipStream_t stream) {
    const int*   x     = (const int*)  d_in[0];
    const float* r     = (const float*)d_in[1];
    const float* emb   = (const float*)d_in[2];
    const float* aw_W  = (const float*)d_in[3];
    const float* aw_b  = (const float*)d_in[4];
    const float* cf_W1 = (const float*)d_in[5];
    const float* cf_b1 = (const float*)d_in[6];
    const float* cf_W2 = (const float*)d_in[7];
    const float* cf_b2 = (const float*)d_in[8];
    const float* n_W1  = (const float*)d_in[9];
    const float* n_b1  = (const float*)d_in[10];
    const float* n_W2  = (const float*)d_in[11];
    const float* n_b2  = (const float*)d_in[12];
    const float* oW1   = (const float*)d_in[13];
    const float* ob1   = (const float*)d_in[14];
    const float* oW2   = (const float*)d_in[15];
    const float* ob2   = (const float*)d_in[16];
    float* out = (float*)d_out;

    char* ws = (char*)d_ws;
    uint2*    dpk  = (uint2*)ws;    ws += (size_t)N_ATOMS * N_ATOMS * 8;      // 2 MB
    float*    h    = (float*)ws;    ws += (size_t)N_ATOMS * F_DIM * 4;        // 256 KB
    unsigned* opkA = (unsigned*)ws; ws += (size_t)N_ATOMS * (F_DIM / 2) * 4;  // 128 KB
    unsigned* opkB = (unsigned*)ws; ws += (size_t)N_ATOMS * (F_DIM / 2) * 4;  // 128 KB
    uint2*    ptab = (uint2*)ws;                                              // 2.7 MB

    void* args[] = {
        (void*)&x, (void*)&r, (void*)&emb, (void*)&aw_W, (void*)&aw_b,
        (void*)&cf_W1, (void*)&cf_b1, (void*)&cf_W2, (void*)&cf_b2,
        (void*)&n_W1, (void*)&n_b1, (void*)&n_W2, (void*)&n_b2,
        (void*)&oW1, (void*)&ob1, (void*)&oW2, (void*)&ob2,
        (void*)&dpk, (void*)&h, (void*)&opkA, (void*)&opkB,
        (void*)&ptab, (void*)&out
    };
    hipError_t err = hipLaunchCooperativeKernel((const void*)fused_kernel,
                                                dim3(N_ATOMS), dim3(256),
                                                args, 0, stream);
    if (err != hipSuccess) {
        // deterministic fallback: round-4 multi-dispatch path
        (void)hipGetLastError();   // clear sticky error
        prep_build<<<N_ATOMS + NBBLK2, 256, 0, stream>>>(
            x, r, emb, aw_W, aw_b, cf_W1, cf_b1, cf_W2, cf_b2, dpk, h, opkA, ptab);
        for (int l = 0; l < NLAYER; ++l) {
            unsigned* oin  = (l & 1) ? opkB : opkA;
            unsigned* oout = (l & 1) ? opkA : opkB;
            convnode_kernel<<<N_ATOMS, 512, 0, stream>>>(
                dpk, oin, ptab, n_W1, n_b1, n_W2, n_b2, h,
                aw_W, aw_b, oout, oW1, ob1, oW2, ob2, out, l);
        }
    }
}

// Round 7
// 173.323 us; speedup vs baseline: 2.8001x; 2.8001x over previous
//
#include <hip/hip_runtime.h>
#include <hip/hip_fp16.h>
#include <math.h>

#define N_ATOMS 512
#define F_DIM   128
#define K_RBF   301
#define NLAYER  3
#define GAMMA_C 10.0f
#define LOG2_C  0.6931471805599453f

// Filter lookup table: w_l(d) sampled at step TAB_H; max d = 10*sqrt(3) = 17.32
#define TAB_H     0.01f
#define TAB_INVH  100.0f
#define TAB_ROWS  1768          // 221 * 8, covers up to 17.67
#define RPB       8             // table rows emitted per task (computes RPB+1)
#define NGROUPS   (TAB_ROWS / RPB)          // 221
#define NTASKS    (NGROUPS * NLAYER)        // 663 (row-group, layer) tasks
#define NBBLK2    ((NTASKS + 1) / 2)        // 332 build blocks, 2 tasks each
#define ROW_BYTES 512           // 64 f-pairs * 8 B (uint2 per pair)
#define JSPLIT    4             // conv j-range split across blocks
#define JCH       (N_ATOMS / JSPLIT)        // 128 j per conv block

__device__ __forceinline__ float ssp(float x) {
    float ax = fabsf(x);
    return fmaxf(x, 0.0f) + log1pf(expf(-ax)) - LOG2_C;
}
__device__ __forceinline__ __half2 u2h2(unsigned u) {
    union { unsigned u; __half2 h; } c; c.u = u; return c.h;
}
__device__ __forceinline__ unsigned h22u(__half2 h) {
    union { unsigned u; __half2 h; } c; c.h = h; return c.u;
}

// ---------------------------------------------------------------------------
// Fused prep + table build.  grid: (512 + 332) x 256   (round-4 proven)
__global__ void __launch_bounds__(256)
prep_build(const int* __restrict__ x, const float* __restrict__ r,
           const float* __restrict__ emb,
           const float* __restrict__ aw_W, const float* __restrict__ aw_b,
           const float* __restrict__ cf_W1, const float* __restrict__ cf_b1,
           const float* __restrict__ cf_W2, const float* __restrict__ cf_b2,
           uint2* __restrict__ dpk, float* __restrict__ h,
           unsigned* __restrict__ opk, uint2* __restrict__ ptab) {
    __shared__ float hs[F_DIM];
    __shared__ float os[F_DIM];
    __shared__ float e_s[2][RPB + 1][34];
    __shared__ float w1_s[2][F_DIM][12];

    if (blockIdx.x < N_ATOMS) {
        // ---- prep path: distances + embedding + layer-0 atomwise ----
        int i = blockIdx.x;
        int t = threadIdx.x;
        float rx = r[i * 3 + 0], ry = r[i * 3 + 1], rz = r[i * 3 + 2];
        if (t < F_DIM) {
            float hv = emb[x[i] * F_DIM + t];
            h[i * F_DIM + t] = hv;
            hs[t] = hv;
        }
        for (int j = t; j < N_ATOMS; j += 256) {
            float dx = rx - r[j * 3 + 0];
            float dy = ry - r[j * 3 + 1];
            float dz = rz - r[j * 3 + 2];
            float d  = sqrtf(dx * dx + dy * dy + dz * dz);
            float xb = d * TAB_INVH;
            int   b  = ::min((int)xb, TAB_ROWS - 2);
            float fr = xb - (float)b;
            __half fh = __float2half(fr);
            dpk[i * N_ATOMS + j] = make_uint2((unsigned)b * ROW_BYTES,
                                              h22u(__halves2half2(fh, fh)));
        }
        __syncthreads();
        if (t < F_DIM) {
            float acc = aw_b[t];
            for (int g = 0; g < F_DIM; ++g) acc = fmaf(hs[g], aw_W[g * F_DIM + t], acc);
            os[t] = acc;
        }
        __syncthreads();
        if (t < F_DIM / 2)
            opk[i * 64 + t] = h22u(__halves2half2(__float2half(os[2 * t]),
                                                  __float2half(os[2 * t + 1])));
        return;
    }

    // ---- build path: 2 (row-group, layer) tasks per block ----
    int u = threadIdx.x >> 7;
    int f = threadIdx.x & 127;
    int task = (blockIdx.x - N_ATOMS) * 2 + u;
    bool valid = task < NTASKS;
    task = valid ? task : NTASKS - 1;
    int l    = task / NGROUPS;
    int row0 = (task % NGROUPS) * RPB;

    float dlo = row0 * TAB_H;
    float dhi = (row0 + RPB) * TAB_H;
    // Gaussian window: exp(-10*1.45^2) ~ 7.6e-10 truncation
    int k0 = ::max(0, (int)ceilf((dlo - 1.45f) * 10.0f));
    int k1 = ::min(K_RBF - 1, (int)floorf((dhi + 1.45f) * 10.0f));
    int kw = k1 - k0 + 1;

    for (int idx = f; idx < (RPB + 1) * kw; idx += F_DIM) {
        int rr = idx / kw, kk = idx % kw;
        float dv = (row0 + rr) * TAB_H;
        float tt = dv - 0.1f * (float)(k0 + kk);
        e_s[u][rr][kk] = expf(-GAMMA_C * tt * tt);
    }
    __syncthreads();

    const float* W1 = cf_W1 + l * K_RBF * F_DIM;
    float b1v = cf_b1[l * F_DIM + f];
    float acc[RPB + 1];
#pragma unroll
    for (int rr = 0; rr <= RPB; ++rr) acc[rr] = b1v;
    for (int kk = 0; kk < kw; ++kk) {
        float w1v = W1[(k0 + kk) * F_DIM + f];
#pragma unroll
        for (int rr = 0; rr <= RPB; ++rr) acc[rr] = fmaf(e_s[u][rr][kk], w1v, acc[rr]);
    }
#pragma unroll
    for (int rr = 0; rr <= RPB; ++rr) w1_s[u][f][rr] = ssp(acc[rr]);
    __syncthreads();

    const float* W2 = cf_W2 + l * F_DIM * F_DIM;
    float b2v = cf_b2[l * F_DIM + f];
    float acc2[RPB + 1];
#pragma unroll
    for (int rr = 0; rr <= RPB; ++rr) acc2[rr] = b2v;
    for (int g = 0; g < F_DIM; ++g) {
        float w2v = W2[g * F_DIM + f];
        float4 wa = *(const float4*)&w1_s[u][g][0];
        float4 wb = *(const float4*)&w1_s[u][g][4];
        float  wc = w1_s[u][g][8];
        acc2[0] = fmaf(wa.x, w2v, acc2[0]);
        acc2[1] = fmaf(wa.y, w2v, acc2[1]);
        acc2[2] = fmaf(wa.z, w2v, acc2[2]);
        acc2[3] = fmaf(wa.w, w2v, acc2[3]);
        acc2[4] = fmaf(wb.x, w2v, acc2[4]);
        acc2[5] = fmaf(wb.y, w2v, acc2[5]);
        acc2[6] = fmaf(wb.z, w2v, acc2[6]);
        acc2[7] = fmaf(wb.w, w2v, acc2[7]);
        acc2[8] = fmaf(wc,   w2v, acc2[8]);
    }
    float o9[RPB + 1];
#pragma unroll
    for (int rr = 0; rr <= RPB; ++rr) o9[rr] = ssp(acc2[rr]);

    // pack via same-wave shfl with lane f^1; even lanes write pair p=f>>1
    if (valid) {
        int p = f >> 1;
        bool odd = (f & 1);
#pragma unroll
        for (int rr = 0; rr < RPB; ++rr) {
            float t0 = o9[rr];
            float dt = o9[rr + 1] - o9[rr];
            float ot0 = __shfl_xor(t0, 1, 64);
            float odt = __shfl_xor(dt, 1, 64);
            if (!odd) {
                uint2 v = make_uint2(
                    h22u(__halves2half2(__float2half(t0), __float2half(ot0))),
                    h22u(__halves2half2(__float2half(dt), __float2half(odt))));
                ptab[((size_t)l * TAB_ROWS + row0 + rr) * 64 + p] = v;
            }
        }
    }
}

// ---------------------------------------------------------------------------
// Conv partial: block (i, s) computes cpart[s,i,f] = sum over j in slice s of
// lerp(ptab_l, d[i,j])[f] * o[j,f].
// grid: (N_ATOMS, JSPLIT) x 512; thread t: pair p=t&63, jc=t>>6 (16 j each).
// __launch_bounds__(512,8): VGPR<=64 -> 8 waves/SIMD -> 2x round-4 hiding.
__global__ void __launch_bounds__(512, 8)
conv_partial(const uint2* __restrict__ dpk, const unsigned* __restrict__ opk_in,
             const uint2* __restrict__ ptab, float* __restrict__ cpart, int l) {
    int i  = blockIdx.x;
    int s  = blockIdx.y;
    int t  = threadIdx.x;
    int p  = t & 63;
    int jc = t >> 6;            // 0..7

    __shared__ uint2  ds[JCH];
    __shared__ float2 red[8][64];

    if (t < JCH) ds[t] = dpk[i * N_ATOMS + s * JCH + t];
    __syncthreads();

    const char*     T  = (const char*)(ptab + (size_t)l * TAB_ROWS * 64) + p * 8;
    const unsigned* ob = opk_in + (s * JCH) * 64 + p;

    float2 acc = make_float2(0.0f, 0.0f);
    int j0 = jc * (JCH / 8);    // 16 j per thread
#pragma unroll 4
    for (int jj = 0; jj < JCH / 8; ++jj) {
        uint2 e = ds[j0 + jj];                   // broadcast: wave-uniform j
        uint2 tv = *(const uint2*)(T + e.x);     // {half2 t0, half2 dt}
        __half2 w2 = __hfma2(u2h2(e.y), u2h2(tv.y), u2h2(tv.x));
        __half2 oh = u2h2(ob[(j0 + jj) * 64]);
        acc.x = fmaf(__half2float(__low2half(w2)),  __half2float(__low2half(oh)),  acc.x);
        acc.y = fmaf(__half2float(__high2half(w2)), __half2float(__high2half(oh)), acc.y);
    }
    red[jc][p] = acc;
    __syncthreads();
    if (jc == 0) {
        float2 v = red[0][p];
#pragma unroll
        for (int q = 1; q < 8; ++q) { v.x += red[q][p].x; v.y += red[q][p].y; }
        *(float2*)&cpart[((size_t)s * N_ATOMS + i) * F_DIM + 2 * p] = v;
    }
}

// ---------------------------------------------------------------------------
// Node: c = sum_s cpart[s]; h += ssp(c @ n_W1 + n_b1) @ n_W2 + n_b2; then the
// next atomwise (l<2, packed half2, double-buffered) or output head (l==2).
// grid: N_ATOMS x 128
__global__ void __launch_bounds__(128)
node_kernel(const float* __restrict__ cpart,
            const float* __restrict__ n_W1, const float* __restrict__ n_b1,
            const float* __restrict__ n_W2, const float* __restrict__ n_b2,
            float* __restrict__ h,
            const float* __restrict__ aw_W, const float* __restrict__ aw_b,
            unsigned* __restrict__ opk_out,
            const float* __restrict__ oW1, const float* __restrict__ ob1,
            const float* __restrict__ oW2, const float* __restrict__ ob2,
            float* __restrict__ out, int l) {
    int i = blockIdx.x, f = threadIdx.x;
    __shared__ float cs[F_DIM];
    __shared__ float t1s[F_DIM];
    __shared__ float hs[F_DIM];

    float cv = 0.0f;
#pragma unroll
    for (int s = 0; s < JSPLIT; ++s)
        cv += cpart[((size_t)s * N_ATOMS + i) * F_DIM + f];
    cs[f] = cv;
    hs[f] = h[i * F_DIM + f];
    __syncthreads();

    const float* W1 = n_W1 + l * F_DIM * F_DIM;
    float a = n_b1[l * F_DIM + f];
    for (int g = 0; g < F_DIM; ++g) a = fmaf(cs[g], W1[g * F_DIM + f], a);
    t1s[f] = ssp(a);
    __syncthreads();

    const float* W2 = n_W2 + l * F_DIM * F_DIM;
    float a2 = n_b2[l * F_DIM + f];
    for (int g = 0; g < F_DIM; ++g) a2 = fmaf(t1s[g], W2[g * F_DIM + f], a2);
    float hv = hs[f] + a2;
    h[i * F_DIM + f] = hv;
    hs[f] = hv;
    __syncthreads();

    if (l < NLAYER - 1) {
        const float* W = aw_W + (l + 1) * F_DIM * F_DIM;
        float av = aw_b[(l + 1) * F_DIM + f];
        for (int g = 0; g < F_DIM; ++g) av = fmaf(hs[g], W[g * F_DIM + f], av);
        t1s[f] = av;
        __syncthreads();
        if (f < F_DIM / 2)
            opk_out[i * 64 + f] = h22u(__halves2half2(__float2half(t1s[2 * f]),
                                                      __float2half(t1s[2 * f + 1])));
    } else {
        float val = 0.0f;
        if (f < 32) {
            float ah = ob1[f];
            for (int g = 0; g < F_DIM; ++g) ah = fmaf(hs[g], oW1[g * 32 + f], ah);
            val = ssp(ah) * oW2[f];
        }
#pragma unroll
        for (int off = 16; off > 0; off >>= 1) val += __shfl_xor(val, off, 64);
        if (f == 0) out[i] = val + ob2[0];
    }
}

// ---------------------------------------------------------------------------
extern "C" void kernel_launch(void* const* d_in, const int* in_sizes, int n_in,
                              void* d_out, int out_size, void* d_ws, size_t ws_size,
                              hipStream_t stream) {
    const int*   x     = (const int*)  d_in[0];
    const float* r     = (const float*)d_in[1];
    const float* emb   = (const float*)d_in[2];
    const float* aw_W  = (const float*)d_in[3];
    const float* aw_b  = (const float*)d_in[4];
    const float* cf_W1 = (const float*)d_in[5];
    const float* cf_b1 = (const float*)d_in[6];
    const float* cf_W2 = (const float*)d_in[7];
    const float* cf_b2 = (const float*)d_in[8];
    const float* n_W1  = (const float*)d_in[9];
    const float* n_b1  = (const float*)d_in[10];
    const float* n_W2  = (const float*)d_in[11];
    const float* n_b2  = (const float*)d_in[12];
    const float* oW1   = (const float*)d_in[13];
    const float* ob1   = (const float*)d_in[14];
    const float* oW2   = (const float*)d_in[15];
    const float* ob2   = (const float*)d_in[16];
    float* out = (float*)d_out;

    char* ws = (char*)d_ws;
    uint2*    dpk   = (uint2*)ws;    ws += (size_t)N_ATOMS * N_ATOMS * 8;          // 2 MB
    float*    h     = (float*)ws;    ws += (size_t)N_ATOMS * F_DIM * 4;            // 256 KB
    unsigned* opkA  = (unsigned*)ws; ws += (size_t)N_ATOMS * (F_DIM / 2) * 4;      // 128 KB
    unsigned* opkB  = (unsigned*)ws; ws += (size_t)N_ATOMS * (F_DIM / 2) * 4;      // 128 KB
    float*    cpart = (float*)ws;    ws += (size_t)JSPLIT * N_ATOMS * F_DIM * 4;   // 1 MB
    uint2*    ptab  = (uint2*)ws;                                                  // 2.7 MB

    prep_build<<<N_ATOMS + NBBLK2, 256, 0, stream>>>(
        x, r, emb, aw_W, aw_b, cf_W1, cf_b1, cf_W2, cf_b2, dpk, h, opkA, ptab);
    for (int l = 0; l < NLAYER; ++l) {
        unsigned* oin  = (l & 1) ? opkB : opkA;
        unsigned* oout = (l & 1) ? opkA : opkB;
        conv_partial<<<dim3(N_ATOMS, JSPLIT), 512, 0, stream>>>(dpk, oin, ptab, cpart, l);
        node_kernel<<<N_ATOMS, 128, 0, stream>>>(
            cpart, n_W1, n_b1, n_W2, n_b2, h,
            aw_W, aw_b, oout, oW1, ob1, oW2, ob2, out, l);
    }
}

// Round 8
// 165.931 us; speedup vs baseline: 2.9249x; 1.0445x over previous
//
#include <hip/hip_runtime.h>
#include <hip/hip_fp16.h>
#include <math.h>

#define N_ATOMS 512
#define F_DIM   128
#define K_RBF   301
#define NLAYER  3
#define GAMMA_C 10.0f
#define LOG2_C  0.6931471805599453f

// Filter lookup table: w_l(d) sampled at step TAB_H; max d = 10*sqrt(3) = 17.32
#define TAB_H     0.01f
#define TAB_INVH  100.0f
#define TAB_ROWS  1768          // 221 * 8, covers up to 17.67
#define RPB       8             // table rows emitted per task (computes RPB+1)
#define NGROUPS   (TAB_ROWS / RPB)          // 221
#define NTASKS    (NGROUPS * NLAYER)        // 663 (row-group, layer) tasks
#define NBBLK2    ((NTASKS + 1) / 2)        // 332 build blocks, 2 tasks each
#define ROW_BYTES 512           // 64 f-pairs * 8 B (uint2 per pair)

__device__ __forceinline__ float ssp(float x) {
    float ax = fabsf(x);
    return fmaxf(x, 0.0f) + log1pf(expf(-ax)) - LOG2_C;
}
__device__ __forceinline__ __half2 u2h2(unsigned u) {
    union { unsigned u; __half2 h; } c; c.u = u; return c.h;
}
__device__ __forceinline__ unsigned h22u(__half2 h) {
    union { unsigned u; __half2 h; } c; c.h = h; return c.u;
}

// ---------------------------------------------------------------------------
// Fused prep + table build.  grid: (512 + 332) x 256   (round-4/7 proven)
__global__ void __launch_bounds__(256)
prep_build(const int* __restrict__ x, const float* __restrict__ r,
           const float* __restrict__ emb,
           const float* __restrict__ aw_W, const float* __restrict__ aw_b,
           const float* __restrict__ cf_W1, const float* __restrict__ cf_b1,
           const float* __restrict__ cf_W2, const float* __restrict__ cf_b2,
           uint2* __restrict__ dpk, float* __restrict__ h,
           unsigned* __restrict__ opk, uint2* __restrict__ ptab) {
    __shared__ float hs[F_DIM];
    __shared__ float os[F_DIM];
    __shared__ float e_s[2][RPB + 1][34];
    __shared__ float w1_s[2][F_DIM][12];

    if (blockIdx.x < N_ATOMS) {
        // ---- prep path: distances + embedding + layer-0 atomwise ----
        int i = blockIdx.x;
        int t = threadIdx.x;
        float rx = r[i * 3 + 0], ry = r[i * 3 + 1], rz = r[i * 3 + 2];
        if (t < F_DIM) {
            float hv = emb[x[i] * F_DIM + t];
            h[i * F_DIM + t] = hv;
            hs[t] = hv;
        }
        for (int j = t; j < N_ATOMS; j += 256) {
            float dx = rx - r[j * 3 + 0];
            float dy = ry - r[j * 3 + 1];
            float dz = rz - r[j * 3 + 2];
            float d  = sqrtf(dx * dx + dy * dy + dz * dz);
            float xb = d * TAB_INVH;
            int   b  = ::min((int)xb, TAB_ROWS - 2);
            float fr = xb - (float)b;
            __half fh = __float2half(fr);
            dpk[i * N_ATOMS + j] = make_uint2((unsigned)b * ROW_BYTES,
                                              h22u(__halves2half2(fh, fh)));
        }
        __syncthreads();
        if (t < F_DIM) {
            float acc = aw_b[t];
            for (int g = 0; g < F_DIM; ++g) acc = fmaf(hs[g], aw_W[g * F_DIM + t], acc);
            os[t] = acc;
        }
        __syncthreads();
        if (t < F_DIM / 2)
            opk[i * 64 + t] = h22u(__halves2half2(__float2half(os[2 * t]),
                                                  __float2half(os[2 * t + 1])));
        return;
    }

    // ---- build path: 2 (row-group, layer) tasks per block ----
    int u = threadIdx.x >> 7;
    int f = threadIdx.x & 127;
    int task = (blockIdx.x - N_ATOMS) * 2 + u;
    bool valid = task < NTASKS;
    task = valid ? task : NTASKS - 1;
    int l    = task / NGROUPS;
    int row0 = (task % NGROUPS) * RPB;

    float dlo = row0 * TAB_H;
    float dhi = (row0 + RPB) * TAB_H;
    // Gaussian window: exp(-10*1.45^2) ~ 7.6e-10 truncation
    int k0 = ::max(0, (int)ceilf((dlo - 1.45f) * 10.0f));
    int k1 = ::min(K_RBF - 1, (int)floorf((dhi + 1.45f) * 10.0f));
    int kw = k1 - k0 + 1;

    for (int idx = f; idx < (RPB + 1) * kw; idx += F_DIM) {
        int rr = idx / kw, kk = idx % kw;
        float dv = (row0 + rr) * TAB_H;
        float tt = dv - 0.1f * (float)(k0 + kk);
        e_s[u][rr][kk] = expf(-GAMMA_C * tt * tt);
    }
    __syncthreads();

    const float* W1 = cf_W1 + l * K_RBF * F_DIM;
    float b1v = cf_b1[l * F_DIM + f];
    float acc[RPB + 1];
#pragma unroll
    for (int rr = 0; rr <= RPB; ++rr) acc[rr] = b1v;
    for (int kk = 0; kk < kw; ++kk) {
        float w1v = W1[(k0 + kk) * F_DIM + f];
#pragma unroll
        for (int rr = 0; rr <= RPB; ++rr) acc[rr] = fmaf(e_s[u][rr][kk], w1v, acc[rr]);
    }
#pragma unroll
    for (int rr = 0; rr <= RPB; ++rr) w1_s[u][f][rr] = ssp(acc[rr]);
    __syncthreads();

    const float* W2 = cf_W2 + l * F_DIM * F_DIM;
    float b2v = cf_b2[l * F_DIM + f];
    float acc2[RPB + 1];
#pragma unroll
    for (int rr = 0; rr <= RPB; ++rr) acc2[rr] = b2v;
    for (int g = 0; g < F_DIM; ++g) {
        float w2v = W2[g * F_DIM + f];
        float4 wa = *(const float4*)&w1_s[u][g][0];
        float4 wb = *(const float4*)&w1_s[u][g][4];
        float  wc = w1_s[u][g][8];
        acc2[0] = fmaf(wa.x, w2v, acc2[0]);
        acc2[1] = fmaf(wa.y, w2v, acc2[1]);
        acc2[2] = fmaf(wa.z, w2v, acc2[2]);
        acc2[3] = fmaf(wa.w, w2v, acc2[3]);
        acc2[4] = fmaf(wb.x, w2v, acc2[4]);
        acc2[5] = fmaf(wb.y, w2v, acc2[5]);
        acc2[6] = fmaf(wb.z, w2v, acc2[6]);
        acc2[7] = fmaf(wb.w, w2v, acc2[7]);
        acc2[8] = fmaf(wc,   w2v, acc2[8]);
    }
    float o9[RPB + 1];
#pragma unroll
    for (int rr = 0; rr <= RPB; ++rr) o9[rr] = ssp(acc2[rr]);

    // pack via same-wave shfl with lane f^1; even lanes write pair p=f>>1
    if (valid) {
        int p = f >> 1;
        bool odd = (f & 1);
#pragma unroll
        for (int rr = 0; rr < RPB; ++rr) {
            float t0 = o9[rr];
            float dt = o9[rr + 1] - o9[rr];
            float ot0 = __shfl_xor(t0, 1, 64);
            float odt = __shfl_xor(dt, 1, 64);
            if (!odd) {
                uint2 v = make_uint2(
                    h22u(__halves2half2(__float2half(t0), __float2half(ot0))),
                    h22u(__halves2half2(__float2half(dt), __float2half(odt))));
                ptab[((size_t)l * TAB_ROWS + row0 + rr) * 64 + p] = v;
            }
        }
    }
}

// ---------------------------------------------------------------------------
// Fused conv + node (+ next atomwise / output head).  grid: N_ATOMS x 512
// Conv lane layout: p2 = t&31 owns features 4p2..4p2+3 (16 B of the table
// row, dwordx4 load); jc = t>>5 in [0,16) covers 32 j each.
// Node MLP: 4-way g-split partials across all 512 threads + LDS combine.
__global__ void __launch_bounds__(512, 4)
convnode_kernel(const uint2* __restrict__ dpk, const unsigned* __restrict__ opk_in,
                const uint2* __restrict__ ptab,
                const float* __restrict__ n_W1, const float* __restrict__ n_b1,
                const float* __restrict__ n_W2, const float* __restrict__ n_b2,
                float* __restrict__ h,
                const float* __restrict__ aw_W, const float* __restrict__ aw_b,
                unsigned* __restrict__ opk_out,
                const float* __restrict__ oW1, const float* __restrict__ ob1,
                const float* __restrict__ oW2, const float* __restrict__ ob2,
                float* __restrict__ out, int l) {
    int i  = blockIdx.x;
    int t  = threadIdx.x;
    int p2 = t & 31;
    int jc = t >> 5;            // 0..15

    __shared__ __align__(16) uint2 ds[N_ATOMS];          // 4 KB
    __shared__ __align__(16) float redbuf[16 * 32 * 4];  // 8 KB, multi-use
    __shared__ __align__(16) float cs[F_DIM];
    __shared__ __align__(16) float t1s[F_DIM];
    __shared__ __align__(16) float hs[F_DIM];

    ds[t] = dpk[i * N_ATOMS + t];
    if (t < F_DIM) hs[t] = h[i * F_DIM + t];
    __syncthreads();

    // ---- conv: 4 features/lane, 32 j per jc group ----
    const char*  T   = (const char*)(ptab + (size_t)l * TAB_ROWS * 64) + p2 * 16;
    const uint2* ob  = (const uint2*)opk_in + p2;        // + j*32 below

    float4 acc = make_float4(0.0f, 0.0f, 0.0f, 0.0f);
    int j0 = jc * 32;
#pragma unroll 4
    for (int jj = 0; jj < 32; ++jj) {
        int j = j0 + jj;
        uint2 e = ds[j];                         // broadcast: wave-uniform per half-wave
        uint4 tv = *(const uint4*)(T + e.x);     // {t0 pair a, dt pair a, t0 pair b, dt pair b}
        uint2 ohu = ob[j * 32];                  // features 4p2..4p2+3 of o_j
        __half2 fr2 = u2h2(e.y);
        __half2 wa = __hfma2(fr2, u2h2(tv.y), u2h2(tv.x));
        __half2 wb = __hfma2(fr2, u2h2(tv.w), u2h2(tv.z));
        __half2 oa = u2h2(ohu.x);
        __half2 obh = u2h2(ohu.y);
        acc.x = fmaf(__half2float(__low2half(wa)),  __half2float(__low2half(oa)),  acc.x);
        acc.y = fmaf(__half2float(__high2half(wa)), __half2float(__high2half(oa)), acc.y);
        acc.z = fmaf(__half2float(__low2half(wb)),  __half2float(__low2half(obh)), acc.z);
        acc.w = fmaf(__half2float(__high2half(wb)), __half2float(__high2half(obh)), acc.w);
    }
    *(float4*)&redbuf[(jc * 32 + p2) * 4] = acc;
    __syncthreads();
    if (t < 32) {
        float4 s = *(const float4*)&redbuf[t * 4];
#pragma unroll
        for (int q = 1; q < 16; ++q) {
            float4 v = *(const float4*)&redbuf[(q * 32 + t) * 4];
            s.x += v.x; s.y += v.y; s.z += v.z; s.w += v.w;
        }
        *(float4*)&cs[4 * t] = s;
    }
    __syncthreads();

    // ---- node MLP, phase A: t1s = ssp(cs @ W1 + b1), 4-way g-split ----
    {
        int q = t >> 7, f = t & 127;             // q in [0,4), 32 g each
        const float* W1 = n_W1 + l * F_DIM * F_DIM;
        float a = 0.0f;
        int g0 = q * 32;
        for (int g = 0; g < 32; ++g) a = fmaf(cs[g0 + g], W1[(g0 + g) * F_DIM + f], a);
        redbuf[q * F_DIM + f] = a;
    }
    __syncthreads();
    if (t < F_DIM) {
        float a = redbuf[t] + redbuf[F_DIM + t] + redbuf[2 * F_DIM + t]
                + redbuf[3 * F_DIM + t] + n_b1[l * F_DIM + t];
        t1s[t] = ssp(a);
    }
    __syncthreads();

    // ---- phase B: h += t1s @ W2 + b2 ----
    {
        int q = t >> 7, f = t & 127;
        const float* W2 = n_W2 + l * F_DIM * F_DIM;
        float a = 0.0f;
        int g0 = q * 32;
        for (int g = 0; g < 32; ++g) a = fmaf(t1s[g0 + g], W2[(g0 + g) * F_DIM + f], a);
        redbuf[q * F_DIM + f] = a;
    }
    __syncthreads();
    if (t < F_DIM) {
        float a2 = redbuf[t] + redbuf[F_DIM + t] + redbuf[2 * F_DIM + t]
                 + redbuf[3 * F_DIM + t] + n_b2[l * F_DIM + t];
        float hv = hs[t] + a2;
        h[i * F_DIM + t] = hv;
        hs[t] = hv;
    }
    __syncthreads();

    if (l < NLAYER - 1) {
        // ---- phase C: next layer's atom-wise linear, packed half2 ----
        {
            int q = t >> 7, f = t & 127;
            const float* W = aw_W + (l + 1) * F_DIM * F_DIM;
            float a = 0.0f;
            int g0 = q * 32;
            for (int g = 0; g < 32; ++g) a = fmaf(hs[g0 + g], W[(g0 + g) * F_DIM + f], a);
            redbuf[q * F_DIM + f] = a;
        }
        __syncthreads();
        if (t < F_DIM) {
            t1s[t] = redbuf[t] + redbuf[F_DIM + t] + redbuf[2 * F_DIM + t]
                   + redbuf[3 * F_DIM + t] + aw_b[(l + 1) * F_DIM + t];
        }
        __syncthreads();
        if (t < F_DIM / 2)
            opk_out[i * 64 + t] = h22u(__halves2half2(__float2half(t1s[2 * t]),
                                                      __float2half(t1s[2 * t + 1])));
    } else {
        // ---- output head: out[i] = ssp(hs @ oW1 + ob1) @ oW2 + ob2 ----
        {
            int q = t >> 5, f = t & 31;          // q in [0,16), 8 g each
            float a = 0.0f;
            int g0 = q * 8;
            for (int g = 0; g < 8; ++g) a = fmaf(hs[g0 + g], oW1[(g0 + g) * 32 + f], a);
            redbuf[q * 32 + f] = a;
        }
        __syncthreads();
        float val = 0.0f;
        if (t < 32) {
            float a = ob1[t];
#pragma unroll
            for (int q = 0; q < 16; ++q) a += redbuf[q * 32 + t];
            val = ssp(a) * oW2[t];
        }
#pragma unroll
        for (int off = 16; off > 0; off >>= 1) val += __shfl_xor(val, off, 64);
        if (t == 0) out[i] = val + ob2[0];
    }
}

// ---------------------------------------------------------------------------
extern "C" void kernel_launch(void* const* d_in, const int* in_sizes, int n_in,
                              void* d_out, int out_size, void* d_ws, size_t ws_size,
                              hipStream_t stream) {
    const int*   x     = (const int*)  d_in[0];
    const float* r     = (const float*)d_in[1];
    const float* emb   = (const float*)d_in[2];
    const float* aw_W  = (const float*)d_in[3];
    const float* aw_b  = (const float*)d_in[4];
    const float* cf_W1 = (const float*)d_in[5];
    const float* cf_b1 = (const float*)d_in[6];
    const float* cf_W2 = (const float*)d_in[7];
    const float* cf_b2 = (const float*)d_in[8];
    const float* n_W1  = (const float*)d_in[9];
    const float* n_b1  = (const float*)d_in[10];
    const float* n_W2  = (const float*)d_in[11];
    const float* n_b2  = (const float*)d_in[12];
    const float* oW1   = (const float*)d_in[13];
    const float* ob1   = (const float*)d_in[14];
    const float* oW2   = (const float*)d_in[15];
    const float* ob2   = (const float*)d_in[16];
    float* out = (float*)d_out;

    char* ws = (char*)d_ws;
    uint2*    dpk  = (uint2*)ws;    ws += (size_t)N_ATOMS * N_ATOMS * 8;      // 2 MB
    float*    h    = (float*)ws;    ws += (size_t)N_ATOMS * F_DIM * 4;        // 256 KB
    unsigned* opkA = (unsigned*)ws; ws += (size_t)N_ATOMS * (F_DIM / 2) * 4;  // 128 KB
    unsigned* opkB = (unsigned*)ws; ws += (size_t)N_ATOMS * (F_DIM / 2) * 4;  // 128 KB
    uint2*    ptab = (uint2*)ws;                                              // 2.7 MB

    prep_build<<<N_ATOMS + NBBLK2, 256, 0, stream>>>(
        x, r, emb, aw_W, aw_b, cf_W1, cf_b1, cf_W2, cf_b2, dpk, h, opkA, ptab);
    for (int l = 0; l < NLAYER; ++l) {
        unsigned* oin  = (l & 1) ? opkB : opkA;
        unsigned* oout = (l & 1) ? opkA : opkB;
        convnode_kernel<<<N_ATOMS, 512, 0, stream>>>(
            dpk, oin, ptab, n_W1, n_b1, n_W2, n_b2, h,
            aw_W, aw_b, oout, oW1, ob1, oW2, ob2, out, l);
    }
}